// Round 9
// baseline (495.722 us; speedup 1.0000x reference)
//
#include <hip/hip_runtime.h>

typedef _Float16 h8 __attribute__((ext_vector_type(8)));
typedef _Float16 h4 __attribute__((ext_vector_type(4)));
typedef float    f4 __attribute__((ext_vector_type(4)));
typedef long long ll2 __attribute__((ext_vector_type(2)));

#define MFMA16(a,b,c) __builtin_amdgcn_mfma_f32_16x16x32_f16((a),(b),(c),0,0,0)
#define MFMAQ(a,b,c)  __builtin_amdgcn_mfma_f32_16x16x16f16((a),(b),(c),0,0,0)

#define NSEQ  5200
#define NNODE 325
#define LE    96
#define LD    144
#define OUTL  48
#define NTHR  192   // 3 waves; wave w owns enc tiles w and w+3, dec tile w

#define SXE   72    // halves stride: K rows
#define SVT   104   // halves stride: Vt rows

// LDS (halves): K[96][72]=6912, Vt[64][104]=6656, misc fp32 (96+144+4)
#define K_OFF    0
#define VT_OFF   6912
#define MISC_OFF 13568
#define LDS_HALVES 14060   // 28,120 B -> 5 blocks/CU by LDS

// ws layout (halves): 10 transposed 64x64 + dc1t[256][64] + dc2t[64][256]
#define WSQ(i)   ((i)*4096)
#define WS_DC1   40960
#define WS_DC2   57344
#define WS_TOTAL 73728

struct Params {
  const float* x_enc; const float* x_dec;
  const float* enc_conv_w; const float* dec_conv_w;
  const float* eWq; const float* ebq; const float* eWk; const float* ebk;
  const float* eWv; const float* ebv; const float* eWo; const float* ebo;
  const float* ec1_w; const float* ec1_b; const float* ec2_w; const float* ec2_b;
  const float* en1_g; const float* en1_b; const float* en2_g; const float* en2_b;
  const float* dWq; const float* dbq; const float* dWk; const float* dbk;
  const float* dWv; const float* dbv; const float* dWo; const float* dbo;
  const float* dc1_w; const float* dc1_b; const float* dc2_w; const float* dc2_b;
  const float* dn2_g; const float* dn2_b; const float* dn3_g; const float* dn3_b;
  const float* proj_w; const float* proj_b;
  float* out;
};

__device__ __forceinline__ float wave_sum(float v){
  v += __shfl_xor(v, 32, 64); v += __shfl_xor(v, 16, 64);
  v += __shfl_xor(v,  8, 64); v += __shfl_xor(v,  4, 64);
  v += __shfl_xor(v,  2, 64); v += __shfl_xor(v,  1, 64);
  return v;
}
__device__ __forceinline__ float q_sum(float v){
  v += __shfl_xor(v, 16, 64); v += __shfl_xor(v, 32, 64); return v;
}

// Build B-frag (k = q*8+j) for K=32 MFMA from T-form reg pair
__device__ __forceinline__ h8 bfrag(h4 ta, h4 tb, int q, int m){
  long long v0 = __builtin_bit_cast(long long, ta);
  long long v1 = __builtin_bit_cast(long long, tb);
  int sl = ((q & 1) * 32) + m;
  long long a00 = __shfl(v0, sl, 64);
  long long a01 = __shfl(v0, sl + 16, 64);
  long long a10 = __shfl(v1, sl, 64);
  long long a11 = __shfl(v1, sl + 16, 64);
  bool hiQ = (q >= 2);
  ll2 r = { hiQ ? a10 : a00, hiQ ? a11 : a01 };
  return __builtin_bit_cast(h8, r);
}

// dual-tile: Y^T = A @ t for two T-form inputs, sharing the A loads (K=32)
__device__ __forceinline__ void mm64T2(const _Float16* __restrict__ A, int lda,
                                       const h4 ta[4], const h4 tb[4],
                                       f4 oa[4], f4 ob[4], int q, int m){
  h8 b0a = bfrag(ta[0], ta[1], q, m);
  h8 b1a = bfrag(ta[2], ta[3], q, m);
  h8 b0b = bfrag(tb[0], tb[1], q, m);
  h8 b1b = bfrag(tb[2], tb[3], q, m);
  #pragma unroll
  for (int nt = 0; nt < 4; ++nt){
    h8 a0 = *(const h8*)(A + (nt*16+m)*lda + q*8);
    h8 a1 = *(const h8*)(A + (nt*16+m)*lda + 32 + q*8);
    f4 ca = {0.f,0.f,0.f,0.f};
    ca = MFMA16(a0, b0a, ca); ca = MFMA16(a1, b1a, ca);
    oa[nt] = ca;
    f4 cb = {0.f,0.f,0.f,0.f};
    cb = MFMA16(a0, b0b, cb); cb = MFMA16(a1, b1b, cb);
    ob[nt] = cb;
  }
}
// single-tile variant (decoder)
__device__ __forceinline__ void mm64T(const _Float16* __restrict__ A, int lda,
                                      const h4 t[4], f4 out[4], int q, int m){
  h8 b0 = bfrag(t[0], t[1], q, m);
  h8 b1 = bfrag(t[2], t[3], q, m);
  #pragma unroll
  for (int nt = 0; nt < 4; ++nt){
    h8 a0 = *(const h8*)(A + (nt*16+m)*lda + q*8);
    h8 a1 = *(const h8*)(A + (nt*16+m)*lda + 32 + q*8);
    f4 c = {0.f,0.f,0.f,0.f};
    c = MFMA16(a0, b0, c);
    c = MFMA16(a1, b1, c);
    out[nt] = c;
  }
}

// LN over d (lane-local 16 + cross-q) -> updates xt
__device__ __forceinline__ void lnT(const f4 vf[4], h4 xt[4],
        const float* __restrict__ g_, const float* __restrict__ b_, int q){
  const int d0 = 4*q;
  float s = 0.f;
  #pragma unroll
  for (int nt = 0; nt < 4; ++nt) s += vf[nt][0]+vf[nt][1]+vf[nt][2]+vf[nt][3];
  s = q_sum(s);
  float mu = s * (1.f/64.f);
  float ss = 0.f;
  #pragma unroll
  for (int nt = 0; nt < 4; ++nt)
    #pragma unroll
    for (int i = 0; i < 4; ++i){ float d = vf[nt][i]-mu; ss += d*d; }
  ss = q_sum(ss);
  float rs = rsqrtf(ss * (1.f/64.f) + 1e-5f);
  #pragma unroll
  for (int nt = 0; nt < 4; ++nt){
    f4 g4 = *(const f4*)(g_ + nt*16 + d0);
    f4 b4 = *(const f4*)(b_ + nt*16 + d0);
    h4 o;
    #pragma unroll
    for (int i = 0; i < 4; ++i) o[i] = (_Float16)((vf[nt][i]-mu)*rs*g4[i] + b4[i]);
    xt[nt] = o;
  }
}

// scores (K=16 MFMA: B = qt T-form directly, no bfrag) + softmax.
// No max-subtraction: scores are pre-scaled by 0.125 and O(0.3) for this net.
__device__ __forceinline__ void scores16(const h4 qt[4], const _Float16* Kb,
                                         h4 pt[6], int q, int m){
  f4 s[6];
  #pragma unroll
  for (int st = 0; st < 6; ++st){
    const _Float16* kr = Kb + (st*16+m)*SXE + 4*q;
    f4 cc = {0.f,0.f,0.f,0.f};
    #pragma unroll
    for (int g = 0; g < 4; ++g)
      cc = MFMAQ(*(const h4*)(kr + g*16), qt[g], cc);
    s[st] = cc;
  }
  float sm = 0.f;
  #pragma unroll
  for (int st = 0; st < 6; ++st)
    #pragma unroll
    for (int i = 0; i < 4; ++i){ float e = __expf(s[st][i]); s[st][i] = e; sm += e; }
  sm = q_sum(sm);
  float r = 1.f/sm;
  #pragma unroll
  for (int st = 0; st < 6; ++st){
    h4 o;
    #pragma unroll
    for (int i = 0; i < 4; ++i) o[i] = (_Float16)(s[st][i]*r);
    pt[st] = o;
  }
}

// dual-tile attention + residual + LN (Wqt pre-scaled by 0.125)
__device__ __forceinline__ void attnT2(h4 xA[4], h4 xB[4],
        const _Float16* K, const _Float16* Vt,
        const _Float16* __restrict__ Wqt, const float* __restrict__ bq,
        const _Float16* __restrict__ Wot, const float* __restrict__ bo,
        const float* __restrict__ g_, const float* __restrict__ b_, int q, int m){
  const int d0 = 4*q;
  f4 cA[4], cB[4];
  mm64T2(Wqt, 64, xA, xB, cA, cB, q, m);
  h4 qA[4], qB[4];
  #pragma unroll
  for (int nt = 0; nt < 4; ++nt){
    f4 b4 = *(const f4*)(bq + nt*16 + d0);
    h4 oA, oB;
    #pragma unroll
    for (int i = 0; i < 4; ++i){
      oA[i] = (_Float16)(cA[nt][i] + b4[i]*0.125f);
      oB[i] = (_Float16)(cB[nt][i] + b4[i]*0.125f);
    }
    qA[nt] = oA; qB[nt] = oB;
  }
  // S-phase per tile (K=16, zero bfrags)
  h4 pA[6], pB[6];
  scores16(qA, K, pA, q, m);
  scores16(qB, K, pB, q, m);
  // Prefetch Wo A-frags: global latency hides across PV + pack + bfrag
  h8 wo0[4], wo1[4];
  #pragma unroll
  for (int nt = 0; nt < 4; ++nt){
    wo0[nt] = *(const h8*)(Wot + (nt*16+m)*64 + q*8);
    wo1[nt] = *(const h8*)(Wot + (nt*16+m)*64 + 32 + q*8);
  }
  // PV (K=16, B = p T-form directly), shared Vt loads
  h4 otA[4], otB[4];
  #pragma unroll
  for (int nt = 0; nt < 4; ++nt){
    const _Float16* vr = Vt + (nt*16+m)*SVT + 4*q;
    f4 ca = {0.f,0.f,0.f,0.f}, cb = {0.f,0.f,0.f,0.f};
    #pragma unroll
    for (int st = 0; st < 6; ++st){
      h4 v = *(const h4*)(vr + st*16);
      ca = MFMAQ(v, pA[st], ca);
      cb = MFMAQ(v, pB[st], cb);
    }
    h4 tA, tB;
    #pragma unroll
    for (int i = 0; i < 4; ++i){ tA[i] = (_Float16)ca[i]; tB[i] = (_Float16)cb[i]; }
    otA[nt] = tA; otB[nt] = tB;
  }
  // O proj (K=32 with prefetched A-frags) + residual + LN
  h8 b0a = bfrag(otA[0], otA[1], q, m), b1a = bfrag(otA[2], otA[3], q, m);
  h8 b0b = bfrag(otB[0], otB[1], q, m), b1b = bfrag(otB[2], otB[3], q, m);
  f4 vfA[4], vfB[4];
  #pragma unroll
  for (int nt = 0; nt < 4; ++nt){
    f4 ca = {0.f,0.f,0.f,0.f};
    ca = MFMA16(wo0[nt], b0a, ca); ca = MFMA16(wo1[nt], b1a, ca);
    f4 cb = {0.f,0.f,0.f,0.f};
    cb = MFMA16(wo0[nt], b0b, cb); cb = MFMA16(wo1[nt], b1b, cb);
    f4 b4 = *(const f4*)(bo + nt*16 + d0);
    #pragma unroll
    for (int i = 0; i < 4; ++i){
      vfA[nt][i] = ca[i] + b4[i] + (float)xA[nt][i];
      vfB[nt][i] = cb[i] + b4[i] + (float)xB[nt][i];
    }
  }
  lnT(vfA, xA, g_, b_, q);
  lnT(vfB, xB, g_, b_, q);
}

// single-tile attention (decoder), Wqt pre-scaled
__device__ __forceinline__ void attnT(h4 xt[4], const _Float16* K, const _Float16* Vt,
        const _Float16* __restrict__ Wqt, const float* __restrict__ bq,
        const _Float16* __restrict__ Wot, const float* __restrict__ bo,
        const float* __restrict__ g_, const float* __restrict__ b_, int q, int m){
  const int d0 = 4*q;
  f4 c[4];
  mm64T(Wqt, 64, xt, c, q, m);
  h4 qt[4];
  #pragma unroll
  for (int nt = 0; nt < 4; ++nt){
    f4 b4 = *(const f4*)(bq + nt*16 + d0);
    h4 o;
    #pragma unroll
    for (int i = 0; i < 4; ++i) o[i] = (_Float16)(c[nt][i] + b4[i]*0.125f);
    qt[nt] = o;
  }
  h4 pt[6];
  scores16(qt, K, pt, q, m);
  h8 wo0[4], wo1[4];
  #pragma unroll
  for (int nt = 0; nt < 4; ++nt){
    wo0[nt] = *(const h8*)(Wot + (nt*16+m)*64 + q*8);
    wo1[nt] = *(const h8*)(Wot + (nt*16+m)*64 + 32 + q*8);
  }
  h4 ot[4];
  #pragma unroll
  for (int nt = 0; nt < 4; ++nt){
    const _Float16* vr = Vt + (nt*16+m)*SVT + 4*q;
    f4 cc = {0.f,0.f,0.f,0.f};
    #pragma unroll
    for (int st = 0; st < 6; ++st)
      cc = MFMAQ(*(const h4*)(vr + st*16), pt[st], cc);
    h4 t;
    #pragma unroll
    for (int i = 0; i < 4; ++i) t[i] = (_Float16)cc[i];
    ot[nt] = t;
  }
  h8 b0 = bfrag(ot[0], ot[1], q, m), b1 = bfrag(ot[2], ot[3], q, m);
  f4 vf[4];
  #pragma unroll
  for (int nt = 0; nt < 4; ++nt){
    f4 cc = {0.f,0.f,0.f,0.f};
    cc = MFMA16(wo0[nt], b0, cc); cc = MFMA16(wo1[nt], b1, cc);
    f4 b4 = *(const f4*)(bo + nt*16 + d0);
    #pragma unroll
    for (int i = 0; i < 4; ++i) vf[nt][i] = cc[i] + b4[i] + (float)xt[nt][i];
  }
  lnT(vf, xt, g_, b_, q);
}

// dual-tile FFN d->d + residual + LN (K=32 path)
__device__ __forceinline__ void ffnT2(h4 xA[4], h4 xB[4],
        const _Float16* __restrict__ W1t, const float* __restrict__ b1,
        const _Float16* __restrict__ W2t, const float* __restrict__ b2,
        const float* __restrict__ g_, const float* __restrict__ b_, int q, int m){
  const int d0 = 4*q;
  f4 cA[4], cB[4];
  mm64T2(W1t, 64, xA, xB, cA, cB, q, m);
  h4 hA[4], hB[4];
  #pragma unroll
  for (int nt = 0; nt < 4; ++nt){
    f4 b4 = *(const f4*)(b1 + nt*16 + d0);
    h4 oA, oB;
    #pragma unroll
    for (int i = 0; i < 4; ++i){
      oA[i] = (_Float16)fmaxf(cA[nt][i] + b4[i], 0.f);
      oB[i] = (_Float16)fmaxf(cB[nt][i] + b4[i], 0.f);
    }
    hA[nt] = oA; hB[nt] = oB;
  }
  f4 yA[4], yB[4];
  mm64T2(W2t, 64, hA, hB, yA, yB, q, m);
  f4 vfA[4], vfB[4];
  #pragma unroll
  for (int nt = 0; nt < 4; ++nt){
    f4 b4 = *(const f4*)(b2 + nt*16 + d0);
    #pragma unroll
    for (int i = 0; i < 4; ++i){
      vfA[nt][i] = yA[nt][i] + b4[i] + (float)xA[nt][i];
      vfB[nt][i] = yB[nt][i] + b4[i] + (float)xB[nt][i];
    }
  }
  lnT(vfA, xA, g_, b_, q);
  lnT(vfB, xB, g_, b_, q);
}

// dual-tile K/V build (shared weight loads)
__device__ __forceinline__ void kvT2(const h4 xA[4], const h4 xB[4], int rA, int rB,
        _Float16* K, _Float16* Vt,
        const _Float16* __restrict__ Wkt, const float* __restrict__ bk,
        const _Float16* __restrict__ Wvt, const float* __restrict__ bv,
        int q, int m){
  const int d0 = 4*q;
  f4 cA[4], cB[4];
  mm64T2(Wkt, 64, xA, xB, cA, cB, q, m);
  #pragma unroll
  for (int nt = 0; nt < 4; ++nt){
    f4 b4 = *(const f4*)(bk + nt*16 + d0);
    h4 oA, oB;
    #pragma unroll
    for (int i = 0; i < 4; ++i){
      oA[i] = (_Float16)(cA[nt][i] + b4[i]);
      oB[i] = (_Float16)(cB[nt][i] + b4[i]);
    }
    *(h4*)(K + (rA+m)*SXE + nt*16 + d0) = oA;
    *(h4*)(K + (rB+m)*SXE + nt*16 + d0) = oB;
  }
  mm64T2(Wvt, 64, xA, xB, cA, cB, q, m);
  #pragma unroll
  for (int nt = 0; nt < 4; ++nt){
    f4 b4 = *(const f4*)(bv + nt*16 + d0);
    #pragma unroll
    for (int i = 0; i < 4; ++i){
      Vt[(nt*16 + d0 + i)*SVT + rA + m] = (_Float16)(cA[nt][i] + b4[i]);
      Vt[(nt*16 + d0 + i)*SVT + rB + m] = (_Float16)(cB[nt][i] + b4[i]);
    }
  }
}

// T-form conv for one row (lane: row, d = nt*16+4q+i)
__device__ __forceinline__ void convT(h4 xt[4], const float* __restrict__ cw,
                                      float xl, float xc, float xr, float cs_mu, int q){
  const int d0 = 4*q;
  #pragma unroll
  for (int nt = 0; nt < 4; ++nt){
    const float* w = cw + 3*(nt*16 + d0);
    float c0[4], c1[4], c2[4];
    #pragma unroll
    for (int i = 0; i < 4; ++i){ c0[i] = w[3*i]; c1[i] = w[3*i+1]; c2[i] = w[3*i+2]; }
    h4 o;
    #pragma unroll
    for (int i = 0; i < 4; ++i)
      o[i] = (_Float16)(c0[i]*xl + c1[i]*xc + c2[i]*xr - (c0[i]+c1[i]+c2[i])*cs_mu);
    xt[nt] = o;
  }
}

// ---- weight prep: fp32 -> fp16 transposed; Wq pre-scaled by 0.125 (exact) ----
__global__ void prep_weights(Params p, _Float16* ws){
  const float* sq[10] = {p.eWq, p.eWk, p.eWv, p.eWo, p.ec1_w, p.ec2_w,
                         p.dWq, p.dWk, p.dWv, p.dWo};
  for (int idx = blockIdx.x*blockDim.x + threadIdx.x; idx < WS_TOTAL;
       idx += gridDim.x*blockDim.x){
    if (idx < WS_DC1){
      int mi = idx >> 12, r = idx & 4095;
      int nn = r >> 6, k = r & 63;
      float sc = (mi == 0 || mi == 6) ? 0.125f : 1.f;
      ws[idx] = (_Float16)(sq[mi][k*64 + nn] * sc);
    } else if (idx < WS_DC2){
      int r = idx - WS_DC1;
      int nn = r >> 6, k = r & 63;
      ws[idx] = (_Float16)p.dc1_w[k*256 + nn];
    } else {
      int r = idx - WS_DC2;
      int nn = r >> 8, k2 = r & 255;
      ws[idx] = (_Float16)p.dc2_w[k2*64 + nn];
    }
  }
}

// waves_per_eu(3,4): occupancy capped at 4 waves/EU -> ~128-reg allocator budget.
// LDS already limits to 5 blocks/CU (3.75 waves/EU): no achievable occupancy lost.
__global__ void __launch_bounds__(NTHR)
__attribute__((amdgpu_waves_per_eu(3, 4)))
GraphTransformer_90237262889124_kernel(Params p, const _Float16* __restrict__ ws)
{
  __shared__ __align__(16) _Float16 lds[LDS_HALVES];
  _Float16* K    = lds + K_OFF;
  _Float16* Vt   = lds + VT_OFF;
  float*    serE = (float*)(lds + MISC_OFF);
  float*    serD = serE + 96;
  float*    stat = serD + 144;

  const int tid = threadIdx.x, lane = tid & 63, wave = tid >> 6;
  const int m = lane & 15, q = lane >> 4;
  const int d0 = 4*q;
  const int b = blockIdx.x / NNODE, n = blockIdx.x % NNODE;

  const _Float16* eWq_t = ws + WSQ(0);
  const _Float16* eWk_t = ws + WSQ(1);
  const _Float16* eWv_t = ws + WSQ(2);
  const _Float16* eWo_t = ws + WSQ(3);
  const _Float16* ec1_t = ws + WSQ(4);
  const _Float16* ec2_t = ws + WSQ(5);
  const _Float16* dWq_t = ws + WSQ(6);
  const _Float16* dWk_t = ws + WSQ(7);
  const _Float16* dWv_t = ws + WSQ(8);
  const _Float16* dWo_t = ws + WSQ(9);
  const _Float16* dc1t  = ws + WS_DC1;
  const _Float16* dc2t  = ws + WS_DC2;

  // ---- P0: series loads ----
  if (tid < LE) serE[tid] = p.x_enc[(b*LE + tid)*NNODE + n];
  if (tid >= 48) serD[tid - 48] = p.x_dec[(b*LD + (tid - 48))*NNODE + n];
  __syncthreads();                       // B1
  // ---- P1: means ----
  if (wave == 0){
    float v = serE[lane] + (lane < 32 ? serE[64 + lane] : 0.f);
    float s = wave_sum(v);
    if (lane == 0) stat[0] = s * (1.f/96.f);
  }
  if (wave == 1){
    float v = (lane < OUTL) ? serD[lane] : 0.f;
    float s = wave_sum(v);
    if (lane == 0) stat[1] = s * (1.f/48.f);
  }
  __syncthreads();                       // B2

  const int rA = wave * 16;              // enc tile A rows
  const int rB = (wave + 3) * 16;        // enc tile B rows
  h4 xA[4], xB[4];
  // ---- P2: enc conv (both tiles) + enc K/V ----
  {
    const float mu = stat[0];
    int lA = rA + m;
    int lmA = lA ? lA-1 : LE-1;
    int lpA = (lA == LE-1) ? 0 : lA+1;
    convT(xA, p.enc_conv_w, serE[lmA], serE[lA], serE[lpA], mu, q);
    int lB = rB + m;
    int lmB = lB - 1;                    // rB >= 48, never wraps low
    int lpB = (lB == LE-1) ? 0 : lB+1;
    convT(xB, p.enc_conv_w, serE[lmB], serE[lB], serE[lpB], mu, q);
    kvT2(xA, xB, rA, rB, K, Vt, eWk_t, p.ebk, eWv_t, p.ebv, q, m);
  }
  __syncthreads();                       // B3: enc K/V visible
  // ---- P3: enc attention + FFN (dual-tile) ----
  attnT2(xA, xB, K, Vt, eWq_t, p.ebq, eWo_t, p.ebo, p.en1_g, p.en1_b, q, m);
  ffnT2(xA, xB, ec1_t, p.ec1_b, ec2_t, p.ec2_b, p.en2_g, p.en2_b, q, m);
  __syncthreads();                       // B4: all attn reads done
  // ---- P4: dec cross K/V from enc_out ----
  kvT2(xA, xB, rA, rB, K, Vt, dWk_t, p.dbk, dWv_t, p.dbv, q, m);
  __syncthreads();                       // B5: dec K/V visible
  // ---- P5: decoder (all 3 waves, one tile each) ----
  {
    h4 xt[4];
    {
      const float mu = stat[1];
      const int gr = 96 + rA + m;
      float xl = serD[gr-1];
      float xc = serD[gr];
      float xr = (gr == LD-1) ? (serD[0] - mu) : serD[gr+1];
      convT(xt, p.dec_conv_w, xl, xc, xr, 0.f, q);
    }
    attnT(xt, K, Vt, dWq_t, p.dbq, dWo_t, p.dbo, p.dn2_g, p.dn2_b, q, m);
    // FFN d->4d->d, 4 hidden chunks; dc1 via K=32 (bfrag), dc2-acc via K=16 (B=ht direct)
    f4 acc[4] = {{0.f,0.f,0.f,0.f},{0.f,0.f,0.f,0.f},{0.f,0.f,0.f,0.f},{0.f,0.f,0.f,0.f}};
    for (int cc = 0; cc < 4; ++cc){
      f4 h[4];
      mm64T(dc1t + cc*4096, 64, xt, h, q, m);
      h4 ht[4];
      #pragma unroll
      for (int nt = 0; nt < 4; ++nt){
        f4 b4 = *(const f4*)(p.dc1_b + cc*64 + nt*16 + d0);
        h4 o;
        #pragma unroll
        for (int i = 0; i < 4; ++i) o[i] = (_Float16)fmaxf(h[nt][i] + b4[i], 0.f);
        ht[nt] = o;
      }
      #pragma unroll
      for (int nt = 0; nt < 4; ++nt){
        const _Float16* ar = dc2t + (nt*16+m)*256 + cc*64 + 4*q;
        #pragma unroll
        for (int g = 0; g < 4; ++g)
          acc[nt] = MFMAQ(*(const h4*)(ar + g*16), ht[g], acc[nt]);
      }
    }
    // final LN(dn3) + proj + enc-mean
    f4 vf[4];
    #pragma unroll
    for (int nt = 0; nt < 4; ++nt){
      f4 b4 = *(const f4*)(p.dc2_b + nt*16 + d0);
      #pragma unroll
      for (int i = 0; i < 4; ++i) vf[nt][i] = acc[nt][i] + b4[i] + (float)xt[nt][i];
    }
    float s = 0.f;
    #pragma unroll
    for (int nt = 0; nt < 4; ++nt) s += vf[nt][0]+vf[nt][1]+vf[nt][2]+vf[nt][3];
    s = q_sum(s);
    float mu = s * (1.f/64.f);
    float ss = 0.f;
    #pragma unroll
    for (int nt = 0; nt < 4; ++nt)
      #pragma unroll
      for (int i = 0; i < 4; ++i){ float d = vf[nt][i]-mu; ss += d*d; }
    ss = q_sum(ss);
    float rs = rsqrtf(ss * (1.f/64.f) + 1e-5f);
    float pp = 0.f;
    #pragma unroll
    for (int nt = 0; nt < 4; ++nt){
      f4 g4 = *(const f4*)(p.dn3_g + nt*16 + d0);
      f4 b4 = *(const f4*)(p.dn3_b + nt*16 + d0);
      f4 w4 = *(const f4*)(p.proj_w + nt*16 + d0);
      #pragma unroll
      for (int i = 0; i < 4; ++i)
        pp += ((vf[nt][i]-mu)*rs*g4[i] + b4[i]) * w4[i];
    }
    pp = q_sum(pp);
    if (q == 0)
      p.out[(b*OUTL + rA + m)*NNODE + n] = pp + p.proj_b[0] + stat[0];
  }
}

extern "C" void kernel_launch(void* const* d_in, const int* in_sizes, int n_in,
                              void* d_out, int out_size, void* d_ws, size_t ws_size,
                              hipStream_t stream) {
  Params p;
  p.x_enc = (const float*)d_in[0];  p.x_dec = (const float*)d_in[1];
  p.enc_conv_w = (const float*)d_in[4];  p.dec_conv_w = (const float*)d_in[5];
  p.eWq = (const float*)d_in[6];   p.ebq = (const float*)d_in[7];
  p.eWk = (const float*)d_in[8];   p.ebk = (const float*)d_in[9];
  p.eWv = (const float*)d_in[10];  p.ebv = (const float*)d_in[11];
  p.eWo = (const float*)d_in[12];  p.ebo = (const float*)d_in[13];
  p.ec1_w = (const float*)d_in[14]; p.ec1_b = (const float*)d_in[15];
  p.ec2_w = (const float*)d_in[16]; p.ec2_b = (const float*)d_in[17];
  p.en1_g = (const float*)d_in[18]; p.en1_b = (const float*)d_in[19];
  p.en2_g = (const float*)d_in[20]; p.en2_b = (const float*)d_in[21];
  p.dWq = (const float*)d_in[22];  p.dbq = (const float*)d_in[23];
  p.dWk = (const float*)d_in[24];  p.dbk = (const float*)d_in[25];
  p.dWv = (const float*)d_in[26];  p.dbv = (const float*)d_in[27];
  p.dWo = (const float*)d_in[28];  p.dbo = (const float*)d_in[29];
  p.dc1_w = (const float*)d_in[30]; p.dc1_b = (const float*)d_in[31];
  p.dc2_w = (const float*)d_in[32]; p.dc2_b = (const float*)d_in[33];
  p.dn2_g = (const float*)d_in[34]; p.dn2_b = (const float*)d_in[35];
  p.dn3_g = (const float*)d_in[36]; p.dn3_b = (const float*)d_in[37];
  p.proj_w = (const float*)d_in[38]; p.proj_b = (const float*)d_in[39];
  p.out = (float*)d_out;

  _Float16* ws = (_Float16*)d_ws;
  prep_weights<<<144, 512, 0, stream>>>(p, ws);
  GraphTransformer_90237262889124_kernel<<<NSEQ, NTHR, 0, stream>>>(p, ws);
}

// Round 10
// 436.210 us; speedup vs baseline: 1.1364x; 1.1364x over previous
//
#include <hip/hip_runtime.h>

typedef _Float16 h8 __attribute__((ext_vector_type(8)));
typedef _Float16 h4 __attribute__((ext_vector_type(4)));
typedef float    f4 __attribute__((ext_vector_type(4)));
typedef long long ll2 __attribute__((ext_vector_type(2)));

#define MFMA16(a,b,c) __builtin_amdgcn_mfma_f32_16x16x32_f16((a),(b),(c),0,0,0)

#define NSEQ  5200
#define NNODE 325
#define LE    96
#define LD    144
#define OUTL  48
#define NTHR  192   // 3 waves; wave w owns enc tiles w and w+3, dec tile w

#define SXE   72    // halves stride: K rows
#define SVT   104   // halves stride: Vt rows

// LDS (halves): K[96][72]=6912, Vt[64][104]=6656, misc fp32 (96+144+4)
#define K_OFF    0
#define VT_OFF   6912
#define MISC_OFF 13568
#define LDS_HALVES 14060   // 28,120 B -> 5 blocks/CU by LDS

// ws layout (halves): 10 transposed 64x64 + dc1t[256][64] + dc2t[64][256]
#define WSQ(i)   ((i)*4096)
#define WS_DC1   40960
#define WS_DC2   57344
#define WS_TOTAL 73728

struct Params {
  const float* x_enc; const float* x_dec;
  const float* enc_conv_w; const float* dec_conv_w;
  const float* eWq; const float* ebq; const float* eWk; const float* ebk;
  const float* eWv; const float* ebv; const float* eWo; const float* ebo;
  const float* ec1_w; const float* ec1_b; const float* ec2_w; const float* ec2_b;
  const float* en1_g; const float* en1_b; const float* en2_g; const float* en2_b;
  const float* dWq; const float* dbq; const float* dWk; const float* dbk;
  const float* dWv; const float* dbv; const float* dWo; const float* dbo;
  const float* dc1_w; const float* dc1_b; const float* dc2_w; const float* dc2_b;
  const float* dn2_g; const float* dn2_b; const float* dn3_g; const float* dn3_b;
  const float* proj_w; const float* proj_b;
  float* out;
};

__device__ __forceinline__ float wave_sum(float v){
  v += __shfl_xor(v, 32, 64); v += __shfl_xor(v, 16, 64);
  v += __shfl_xor(v,  8, 64); v += __shfl_xor(v,  4, 64);
  v += __shfl_xor(v,  2, 64); v += __shfl_xor(v,  1, 64);
  return v;
}
__device__ __forceinline__ float q_sum(float v){
  v += __shfl_xor(v, 16, 64); v += __shfl_xor(v, 32, 64); return v;
}

// Build B-frag (k = q*8+j) for K=32 MFMA from T-form reg pair (verified R5/R6/R8)
__device__ __forceinline__ h8 bfrag(h4 ta, h4 tb, int q, int m){
  long long v0 = __builtin_bit_cast(long long, ta);
  long long v1 = __builtin_bit_cast(long long, tb);
  int sl = ((q & 1) * 32) + m;
  long long a00 = __shfl(v0, sl, 64);
  long long a01 = __shfl(v0, sl + 16, 64);
  long long a10 = __shfl(v1, sl, 64);
  long long a11 = __shfl(v1, sl + 16, 64);
  bool hiQ = (q >= 2);
  ll2 r = { hiQ ? a10 : a00, hiQ ? a11 : a01 };
  return __builtin_bit_cast(h8, r);
}

// dual-tile: Y^T = A @ t for two T-form inputs, sharing the A loads (K=32)
__device__ __forceinline__ void mm64T2(const _Float16* __restrict__ A, int lda,
                                       const h4 ta[4], const h4 tb[4],
                                       f4 oa[4], f4 ob[4], int q, int m){
  h8 b0a = bfrag(ta[0], ta[1], q, m);
  h8 b1a = bfrag(ta[2], ta[3], q, m);
  h8 b0b = bfrag(tb[0], tb[1], q, m);
  h8 b1b = bfrag(tb[2], tb[3], q, m);
  #pragma unroll
  for (int nt = 0; nt < 4; ++nt){
    h8 a0 = *(const h8*)(A + (nt*16+m)*lda + q*8);
    h8 a1 = *(const h8*)(A + (nt*16+m)*lda + 32 + q*8);
    f4 ca = {0.f,0.f,0.f,0.f};
    ca = MFMA16(a0, b0a, ca); ca = MFMA16(a1, b1a, ca);
    oa[nt] = ca;
    f4 cb = {0.f,0.f,0.f,0.f};
    cb = MFMA16(a0, b0b, cb); cb = MFMA16(a1, b1b, cb);
    ob[nt] = cb;
  }
}
// single-tile variant (decoder)
__device__ __forceinline__ void mm64T(const _Float16* __restrict__ A, int lda,
                                      const h4 t[4], f4 out[4], int q, int m){
  h8 b0 = bfrag(t[0], t[1], q, m);
  h8 b1 = bfrag(t[2], t[3], q, m);
  #pragma unroll
  for (int nt = 0; nt < 4; ++nt){
    h8 a0 = *(const h8*)(A + (nt*16+m)*lda + q*8);
    h8 a1 = *(const h8*)(A + (nt*16+m)*lda + 32 + q*8);
    f4 c = {0.f,0.f,0.f,0.f};
    c = MFMA16(a0, b0, c);
    c = MFMA16(a1, b1, c);
    out[nt] = c;
  }
}

// LN over d (lane-local 16 + cross-q) -> updates xt
__device__ __forceinline__ void lnT(const f4 vf[4], h4 xt[4],
        const float* __restrict__ g_, const float* __restrict__ b_, int q){
  const int d0 = 4*q;
  float s = 0.f;
  #pragma unroll
  for (int nt = 0; nt < 4; ++nt) s += vf[nt][0]+vf[nt][1]+vf[nt][2]+vf[nt][3];
  s = q_sum(s);
  float mu = s * (1.f/64.f);
  float ss = 0.f;
  #pragma unroll
  for (int nt = 0; nt < 4; ++nt)
    #pragma unroll
    for (int i = 0; i < 4; ++i){ float d = vf[nt][i]-mu; ss += d*d; }
  ss = q_sum(ss);
  float rs = rsqrtf(ss * (1.f/64.f) + 1e-5f);
  #pragma unroll
  for (int nt = 0; nt < 4; ++nt){
    f4 g4 = *(const f4*)(g_ + nt*16 + d0);
    f4 b4 = *(const f4*)(b_ + nt*16 + d0);
    h4 o;
    #pragma unroll
    for (int i = 0; i < 4; ++i) o[i] = (_Float16)((vf[nt][i]-mu)*rs*g4[i] + b4[i]);
    xt[nt] = o;
  }
}

// per-tile scores (K=32 via bfrag) + max-free softmax.
// Scores pre-scaled by 0.125 via Wq; magnitudes O(0.3) for this net -> exp safe
// (validated R9: absmax unchanged at 1.95e-3).
__device__ __forceinline__ void scoresT(const h4 qt[4], const _Float16* Kb,
                                        h4 pt[6], int q, int m){
  h8 qb0 = bfrag(qt[0], qt[1], q, m);
  h8 qb1 = bfrag(qt[2], qt[3], q, m);
  f4 s[6];
  #pragma unroll
  for (int st = 0; st < 6; ++st){
    h8 a0 = *(const h8*)(Kb + (st*16+m)*SXE + q*8);
    h8 a1 = *(const h8*)(Kb + (st*16+m)*SXE + 32 + q*8);
    f4 cc = {0.f,0.f,0.f,0.f};
    cc = MFMA16(a0, qb0, cc); cc = MFMA16(a1, qb1, cc);
    s[st] = cc;
  }
  float sm = 0.f;
  #pragma unroll
  for (int st = 0; st < 6; ++st)
    #pragma unroll
    for (int i = 0; i < 4; ++i){ float e = __expf(s[st][i]); s[st][i] = e; sm += e; }
  sm = q_sum(sm);
  float r = 1.f/sm;
  #pragma unroll
  for (int st = 0; st < 6; ++st){
    h4 o;
    #pragma unroll
    for (int i = 0; i < 4; ++i) o[i] = (_Float16)(s[st][i]*r);
    pt[st] = o;
  }
}

// dual-tile attention + residual + LN (Wqt pre-scaled by 0.125)
__device__ __forceinline__ void attnT2(h4 xA[4], h4 xB[4],
        const _Float16* K, const _Float16* Vt,
        const _Float16* __restrict__ Wqt, const float* __restrict__ bq,
        const _Float16* __restrict__ Wot, const float* __restrict__ bo,
        const float* __restrict__ g_, const float* __restrict__ b_, int q, int m){
  const int d0 = 4*q;
  f4 cA[4], cB[4];
  mm64T2(Wqt, 64, xA, xB, cA, cB, q, m);
  h4 qA[4], qB[4];
  #pragma unroll
  for (int nt = 0; nt < 4; ++nt){
    f4 b4 = *(const f4*)(bq + nt*16 + d0);
    h4 oA, oB;
    #pragma unroll
    for (int i = 0; i < 4; ++i){
      oA[i] = (_Float16)(cA[nt][i] + b4[i]*0.125f);
      oB[i] = (_Float16)(cB[nt][i] + b4[i]*0.125f);
    }
    qA[nt] = oA; qB[nt] = oB;
  }
  // S-phase split per tile (liveness control, R8-verified)
  h4 pA[6], pB[6];
  scoresT(qA, K, pA, q, m);
  scoresT(qB, K, pB, q, m);
  // Prefetch Wo A-frags: global latency hides across PV + pack + bfrag
  h8 wo0[4], wo1[4];
  #pragma unroll
  for (int nt = 0; nt < 4; ++nt){
    wo0[nt] = *(const h8*)(Wot + (nt*16+m)*64 + q*8);
    wo1[nt] = *(const h8*)(Wot + (nt*16+m)*64 + 32 + q*8);
  }
  // O^T = V^T @ P^T (K=32), shared V loads
  h8 pb0A = bfrag(pA[0], pA[1], q, m), pb1A = bfrag(pA[2], pA[3], q, m), pb2A = bfrag(pA[4], pA[5], q, m);
  h8 pb0B = bfrag(pB[0], pB[1], q, m), pb1B = bfrag(pB[2], pB[3], q, m), pb2B = bfrag(pB[4], pB[5], q, m);
  h4 otA[4], otB[4];
  #pragma unroll
  for (int nt = 0; nt < 4; ++nt){
    const _Float16* vr = Vt + (nt*16+m)*SVT;
    h8 v0 = *(const h8*)(vr + q*8);
    h8 v1 = *(const h8*)(vr + 32 + q*8);
    h8 v2 = *(const h8*)(vr + 64 + q*8);
    f4 ca = {0.f,0.f,0.f,0.f};
    ca = MFMA16(v0, pb0A, ca); ca = MFMA16(v1, pb1A, ca); ca = MFMA16(v2, pb2A, ca);
    f4 cb = {0.f,0.f,0.f,0.f};
    cb = MFMA16(v0, pb0B, cb); cb = MFMA16(v1, pb1B, cb); cb = MFMA16(v2, pb2B, cb);
    h4 tA, tB;
    #pragma unroll
    for (int i = 0; i < 4; ++i){ tA[i] = (_Float16)ca[i]; tB[i] = (_Float16)cb[i]; }
    otA[nt] = tA; otB[nt] = tB;
  }
  // O proj (K=32 with prefetched A-frags) + residual + LN
  h8 b0a = bfrag(otA[0], otA[1], q, m), b1a = bfrag(otA[2], otA[3], q, m);
  h8 b0b = bfrag(otB[0], otB[1], q, m), b1b = bfrag(otB[2], otB[3], q, m);
  f4 vfA[4], vfB[4];
  #pragma unroll
  for (int nt = 0; nt < 4; ++nt){
    f4 ca = {0.f,0.f,0.f,0.f};
    ca = MFMA16(wo0[nt], b0a, ca); ca = MFMA16(wo1[nt], b1a, ca);
    f4 cb = {0.f,0.f,0.f,0.f};
    cb = MFMA16(wo0[nt], b0b, cb); cb = MFMA16(wo1[nt], b1b, cb);
    f4 b4 = *(const f4*)(bo + nt*16 + d0);
    #pragma unroll
    for (int i = 0; i < 4; ++i){
      vfA[nt][i] = ca[i] + b4[i] + (float)xA[nt][i];
      vfB[nt][i] = cb[i] + b4[i] + (float)xB[nt][i];
    }
  }
  lnT(vfA, xA, g_, b_, q);
  lnT(vfB, xB, g_, b_, q);
}

// single-tile attention (decoder), Wqt pre-scaled
__device__ __forceinline__ void attnT(h4 xt[4], const _Float16* K, const _Float16* Vt,
        const _Float16* __restrict__ Wqt, const float* __restrict__ bq,
        const _Float16* __restrict__ Wot, const float* __restrict__ bo,
        const float* __restrict__ g_, const float* __restrict__ b_, int q, int m){
  const int d0 = 4*q;
  f4 c[4];
  mm64T(Wqt, 64, xt, c, q, m);
  h4 qt[4];
  #pragma unroll
  for (int nt = 0; nt < 4; ++nt){
    f4 b4 = *(const f4*)(bq + nt*16 + d0);
    h4 o;
    #pragma unroll
    for (int i = 0; i < 4; ++i) o[i] = (_Float16)(c[nt][i] + b4[i]*0.125f);
    qt[nt] = o;
  }
  h4 pt[6];
  scoresT(qt, K, pt, q, m);
  h8 wo0[4], wo1[4];
  #pragma unroll
  for (int nt = 0; nt < 4; ++nt){
    wo0[nt] = *(const h8*)(Wot + (nt*16+m)*64 + q*8);
    wo1[nt] = *(const h8*)(Wot + (nt*16+m)*64 + 32 + q*8);
  }
  h8 pb0 = bfrag(pt[0], pt[1], q, m), pb1 = bfrag(pt[2], pt[3], q, m), pb2 = bfrag(pt[4], pt[5], q, m);
  h4 ot[4];
  #pragma unroll
  for (int nt = 0; nt < 4; ++nt){
    const _Float16* vr = Vt + (nt*16+m)*SVT;
    f4 cc = {0.f,0.f,0.f,0.f};
    cc = MFMA16(*(const h8*)(vr + q*8),      pb0, cc);
    cc = MFMA16(*(const h8*)(vr + 32 + q*8), pb1, cc);
    cc = MFMA16(*(const h8*)(vr + 64 + q*8), pb2, cc);
    h4 t;
    #pragma unroll
    for (int i = 0; i < 4; ++i) t[i] = (_Float16)cc[i];
    ot[nt] = t;
  }
  h8 b0 = bfrag(ot[0], ot[1], q, m), b1 = bfrag(ot[2], ot[3], q, m);
  f4 vf[4];
  #pragma unroll
  for (int nt = 0; nt < 4; ++nt){
    f4 cc = {0.f,0.f,0.f,0.f};
    cc = MFMA16(wo0[nt], b0, cc); cc = MFMA16(wo1[nt], b1, cc);
    f4 b4 = *(const f4*)(bo + nt*16 + d0);
    #pragma unroll
    for (int i = 0; i < 4; ++i) vf[nt][i] = cc[i] + b4[i] + (float)xt[nt][i];
  }
  lnT(vf, xt, g_, b_, q);
}

// dual-tile FFN d->d + residual + LN
__device__ __forceinline__ void ffnT2(h4 xA[4], h4 xB[4],
        const _Float16* __restrict__ W1t, const float* __restrict__ b1,
        const _Float16* __restrict__ W2t, const float* __restrict__ b2,
        const float* __restrict__ g_, const float* __restrict__ b_, int q, int m){
  const int d0 = 4*q;
  f4 cA[4], cB[4];
  mm64T2(W1t, 64, xA, xB, cA, cB, q, m);
  h4 hA[4], hB[4];
  #pragma unroll
  for (int nt = 0; nt < 4; ++nt){
    f4 b4 = *(const f4*)(b1 + nt*16 + d0);
    h4 oA, oB;
    #pragma unroll
    for (int i = 0; i < 4; ++i){
      oA[i] = (_Float16)fmaxf(cA[nt][i] + b4[i], 0.f);
      oB[i] = (_Float16)fmaxf(cB[nt][i] + b4[i], 0.f);
    }
    hA[nt] = oA; hB[nt] = oB;
  }
  f4 yA[4], yB[4];
  mm64T2(W2t, 64, hA, hB, yA, yB, q, m);
  f4 vfA[4], vfB[4];
  #pragma unroll
  for (int nt = 0; nt < 4; ++nt){
    f4 b4 = *(const f4*)(b2 + nt*16 + d0);
    #pragma unroll
    for (int i = 0; i < 4; ++i){
      vfA[nt][i] = yA[nt][i] + b4[i] + (float)xA[nt][i];
      vfB[nt][i] = yB[nt][i] + b4[i] + (float)xB[nt][i];
    }
  }
  lnT(vfA, xA, g_, b_, q);
  lnT(vfB, xB, g_, b_, q);
}

// dual-tile K/V build (shared weight loads)
__device__ __forceinline__ void kvT2(const h4 xA[4], const h4 xB[4], int rA, int rB,
        _Float16* K, _Float16* Vt,
        const _Float16* __restrict__ Wkt, const float* __restrict__ bk,
        const _Float16* __restrict__ Wvt, const float* __restrict__ bv,
        int q, int m){
  const int d0 = 4*q;
  f4 cA[4], cB[4];
  mm64T2(Wkt, 64, xA, xB, cA, cB, q, m);
  #pragma unroll
  for (int nt = 0; nt < 4; ++nt){
    f4 b4 = *(const f4*)(bk + nt*16 + d0);
    h4 oA, oB;
    #pragma unroll
    for (int i = 0; i < 4; ++i){
      oA[i] = (_Float16)(cA[nt][i] + b4[i]);
      oB[i] = (_Float16)(cB[nt][i] + b4[i]);
    }
    *(h4*)(K + (rA+m)*SXE + nt*16 + d0) = oA;
    *(h4*)(K + (rB+m)*SXE + nt*16 + d0) = oB;
  }
  mm64T2(Wvt, 64, xA, xB, cA, cB, q, m);
  #pragma unroll
  for (int nt = 0; nt < 4; ++nt){
    f4 b4 = *(const f4*)(bv + nt*16 + d0);
    #pragma unroll
    for (int i = 0; i < 4; ++i){
      Vt[(nt*16 + d0 + i)*SVT + rA + m] = (_Float16)(cA[nt][i] + b4[i]);
      Vt[(nt*16 + d0 + i)*SVT + rB + m] = (_Float16)(cB[nt][i] + b4[i]);
    }
  }
}

// T-form conv for one row (lane: row, d = nt*16+4q+i)
__device__ __forceinline__ void convT(h4 xt[4], const float* __restrict__ cw,
                                      float xl, float xc, float xr, float cs_mu, int q){
  const int d0 = 4*q;
  #pragma unroll
  for (int nt = 0; nt < 4; ++nt){
    const float* w = cw + 3*(nt*16 + d0);
    float c0[4], c1[4], c2[4];
    #pragma unroll
    for (int i = 0; i < 4; ++i){ c0[i] = w[3*i]; c1[i] = w[3*i+1]; c2[i] = w[3*i+2]; }
    h4 o;
    #pragma unroll
    for (int i = 0; i < 4; ++i)
      o[i] = (_Float16)(c0[i]*xl + c1[i]*xc + c2[i]*xr - (c0[i]+c1[i]+c2[i])*cs_mu);
    xt[nt] = o;
  }
}

// ---- weight prep: fp32 -> fp16 transposed; Wq pre-scaled by 0.125 (exact) ----
__global__ void prep_weights(Params p, _Float16* ws){
  const float* sq[10] = {p.eWq, p.eWk, p.eWv, p.eWo, p.ec1_w, p.ec2_w,
                         p.dWq, p.dWk, p.dWv, p.dWo};
  for (int idx = blockIdx.x*blockDim.x + threadIdx.x; idx < WS_TOTAL;
       idx += gridDim.x*blockDim.x){
    if (idx < WS_DC1){
      int mi = idx >> 12, r = idx & 4095;
      int nn = r >> 6, k = r & 63;
      float sc = (mi == 0 || mi == 6) ? 0.125f : 1.f;
      ws[idx] = (_Float16)(sq[mi][k*64 + nn] * sc);
    } else if (idx < WS_DC2){
      int r = idx - WS_DC1;
      int nn = r >> 6, k = r & 63;
      ws[idx] = (_Float16)p.dc1_w[k*256 + nn];
    } else {
      int r = idx - WS_DC2;
      int nn = r >> 8, k2 = r & 255;
      ws[idx] = (_Float16)p.dc2_w[k2*64 + nn];
    }
  }
}

// waves_per_eu(3,4): occupancy capped at 4 waves/EU -> ~128-reg allocator budget.
// LDS already limits to 5 blocks/CU (3.75 waves/EU): no achievable occupancy lost.
// (R8-verified: kills all scratch spill — WRITE_SIZE 93 MB -> 7.755 MB.)
__global__ void __launch_bounds__(NTHR)
__attribute__((amdgpu_waves_per_eu(3, 4)))
GraphTransformer_90237262889124_kernel(Params p, const _Float16* __restrict__ ws)
{
  __shared__ __align__(16) _Float16 lds[LDS_HALVES];
  _Float16* K    = lds + K_OFF;
  _Float16* Vt   = lds + VT_OFF;
  float*    serE = (float*)(lds + MISC_OFF);
  float*    serD = serE + 96;
  float*    stat = serD + 144;

  const int tid = threadIdx.x, lane = tid & 63, wave = tid >> 6;
  const int m = lane & 15, q = lane >> 4;
  const int d0 = 4*q;
  const int b = blockIdx.x / NNODE, n = blockIdx.x % NNODE;

  const _Float16* eWq_t = ws + WSQ(0);
  const _Float16* eWk_t = ws + WSQ(1);
  const _Float16* eWv_t = ws + WSQ(2);
  const _Float16* eWo_t = ws + WSQ(3);
  const _Float16* ec1_t = ws + WSQ(4);
  const _Float16* ec2_t = ws + WSQ(5);
  const _Float16* dWq_t = ws + WSQ(6);
  const _Float16* dWk_t = ws + WSQ(7);
  const _Float16* dWv_t = ws + WSQ(8);
  const _Float16* dWo_t = ws + WSQ(9);
  const _Float16* dc1t  = ws + WS_DC1;
  const _Float16* dc2t  = ws + WS_DC2;

  // ---- P0: series loads ----
  if (tid < LE) serE[tid] = p.x_enc[(b*LE + tid)*NNODE + n];
  if (tid >= 48) serD[tid - 48] = p.x_dec[(b*LD + (tid - 48))*NNODE + n];
  __syncthreads();                       // B1
  // ---- P1: means ----
  if (wave == 0){
    float v = serE[lane] + (lane < 32 ? serE[64 + lane] : 0.f);
    float s = wave_sum(v);
    if (lane == 0) stat[0] = s * (1.f/96.f);
  }
  if (wave == 1){
    float v = (lane < OUTL) ? serD[lane] : 0.f;
    float s = wave_sum(v);
    if (lane == 0) stat[1] = s * (1.f/48.f);
  }
  __syncthreads();                       // B2

  const int rA = wave * 16;              // enc tile A rows
  const int rB = (wave + 3) * 16;        // enc tile B rows
  h4 xA[4], xB[4];
  // ---- P2: enc conv (both tiles) + enc K/V ----
  {
    const float mu = stat[0];
    int lA = rA + m;
    int lmA = lA ? lA-1 : LE-1;
    int lpA = (lA == LE-1) ? 0 : lA+1;
    convT(xA, p.enc_conv_w, serE[lmA], serE[lA], serE[lpA], mu, q);
    int lB = rB + m;
    int lmB = lB - 1;                    // rB >= 48, never wraps low
    int lpB = (lB == LE-1) ? 0 : lB+1;
    convT(xB, p.enc_conv_w, serE[lmB], serE[lB], serE[lpB], mu, q);
    kvT2(xA, xB, rA, rB, K, Vt, eWk_t, p.ebk, eWv_t, p.ebv, q, m);
  }
  __syncthreads();                       // B3: enc K/V visible
  // ---- P3: enc attention + FFN (dual-tile) ----
  attnT2(xA, xB, K, Vt, eWq_t, p.ebq, eWo_t, p.ebo, p.en1_g, p.en1_b, q, m);
  ffnT2(xA, xB, ec1_t, p.ec1_b, ec2_t, p.ec2_b, p.en2_g, p.en2_b, q, m);
  __syncthreads();                       // B4: all attn reads done
  // ---- P4: dec cross K/V from enc_out; dec conv hoisted (independent of K/V) ----
  h4 xt[4];
  {
    const float mu = stat[1];
    const int gr = 96 + rA + m;
    float xl = serD[gr-1];
    float xc = serD[gr];
    float xr = (gr == LD-1) ? (serD[0] - mu) : serD[gr+1];
    convT(xt, p.dec_conv_w, xl, xc, xr, 0.f, q);
  }
  kvT2(xA, xB, rA, rB, K, Vt, dWk_t, p.dbk, dWv_t, p.dbv, q, m);
  __syncthreads();                       // B5: dec K/V visible
  // ---- P5: decoder (all 3 waves, one tile each) ----
  {
    attnT(xt, K, Vt, dWq_t, p.dbq, dWo_t, p.dbo, p.dn2_g, p.dn2_b, q, m);
    // FFN d->4d->d, 4 hidden chunks, acc in T-form regs (K=32 path)
    f4 acc[4] = {{0.f,0.f,0.f,0.f},{0.f,0.f,0.f,0.f},{0.f,0.f,0.f,0.f},{0.f,0.f,0.f,0.f}};
    for (int cc = 0; cc < 4; ++cc){
      f4 h[4];
      mm64T(dc1t + cc*4096, 64, xt, h, q, m);
      h4 ht[4];
      #pragma unroll
      for (int nt = 0; nt < 4; ++nt){
        f4 b4 = *(const f4*)(p.dc1_b + cc*64 + nt*16 + d0);
        h4 o;
        #pragma unroll
        for (int i = 0; i < 4; ++i) o[i] = (_Float16)fmaxf(h[nt][i] + b4[i], 0.f);
        ht[nt] = o;
      }
      h8 b0 = bfrag(ht[0], ht[1], q, m);
      h8 b1 = bfrag(ht[2], ht[3], q, m);
      #pragma unroll
      for (int nt = 0; nt < 4; ++nt){
        h8 a0 = *(const h8*)(dc2t + (nt*16+m)*256 + cc*64 + q*8);
        h8 a1 = *(const h8*)(dc2t + (nt*16+m)*256 + cc*64 + 32 + q*8);
        acc[nt] = MFMA16(a0, b0, acc[nt]);
        acc[nt] = MFMA16(a1, b1, acc[nt]);
      }
    }
    // final LN(dn3) + proj + enc-mean
    f4 vf[4];
    #pragma unroll
    for (int nt = 0; nt < 4; ++nt){
      f4 b4 = *(const f4*)(p.dc2_b + nt*16 + d0);
      #pragma unroll
      for (int i = 0; i < 4; ++i) vf[nt][i] = acc[nt][i] + b4[i] + (float)xt[nt][i];
    }
    float s = 0.f;
    #pragma unroll
    for (int nt = 0; nt < 4; ++nt) s += vf[nt][0]+vf[nt][1]+vf[nt][2]+vf[nt][3];
    s = q_sum(s);
    float mu = s * (1.f/64.f);
    float ss = 0.f;
    #pragma unroll
    for (int nt = 0; nt < 4; ++nt)
      #pragma unroll
      for (int i = 0; i < 4; ++i){ float d = vf[nt][i]-mu; ss += d*d; }
    ss = q_sum(ss);
    float rs = rsqrtf(ss * (1.f/64.f) + 1e-5f);
    float pp = 0.f;
    #pragma unroll
    for (int nt = 0; nt < 4; ++nt){
      f4 g4 = *(const f4*)(p.dn3_g + nt*16 + d0);
      f4 b4 = *(const f4*)(p.dn3_b + nt*16 + d0);
      f4 w4 = *(const f4*)(p.proj_w + nt*16 + d0);
      #pragma unroll
      for (int i = 0; i < 4; ++i)
        pp += ((vf[nt][i]-mu)*rs*g4[i] + b4[i]) * w4[i];
    }
    pp = q_sum(pp);
    if (q == 0)
      p.out[(b*OUTL + rA + m)*NNODE + n] = pp + p.proj_b[0] + stat[0];
  }
}

extern "C" void kernel_launch(void* const* d_in, const int* in_sizes, int n_in,
                              void* d_out, int out_size, void* d_ws, size_t ws_size,
                              hipStream_t stream) {
  Params p;
  p.x_enc = (const float*)d_in[0];  p.x_dec = (const float*)d_in[1];
  p.enc_conv_w = (const float*)d_in[4];  p.dec_conv_w = (const float*)d_in[5];
  p.eWq = (const float*)d_in[6];   p.ebq = (const float*)d_in[7];
  p.eWk = (const float*)d_in[8];   p.ebk = (const float*)d_in[9];
  p.eWv = (const float*)d_in[10];  p.ebv = (const float*)d_in[11];
  p.eWo = (const float*)d_in[12];  p.ebo = (const float*)d_in[13];
  p.ec1_w = (const float*)d_in[14]; p.ec1_b = (const float*)d_in[15];
  p.ec2_w = (const float*)d_in[16]; p.ec2_b = (const float*)d_in[17];
  p.en1_g = (const float*)d_in[18]; p.en1_b = (const float*)d_in[19];
  p.en2_g = (const float*)d_in[20]; p.en2_b = (const float*)d_in[21];
  p.dWq = (const float*)d_in[22];  p.dbq = (const float*)d_in[23];
  p.dWk = (const float*)d_in[24];  p.dbk = (const float*)d_in[25];
  p.dWv = (const float*)d_in[26];  p.dbv = (const float*)d_in[27];
  p.dWo = (const float*)d_in[28];  p.dbo = (const float*)d_in[29];
  p.dc1_w = (const float*)d_in[30]; p.dc1_b = (const float*)d_in[31];
  p.dc2_w = (const float*)d_in[32]; p.dc2_b = (const float*)d_in[33];
  p.dn2_g = (const float*)d_in[34]; p.dn2_b = (const float*)d_in[35];
  p.dn3_g = (const float*)d_in[36]; p.dn3_b = (const float*)d_in[37];
  p.proj_w = (const float*)d_in[38]; p.proj_b = (const float*)d_in[39];
  p.out = (float*)d_out;

  _Float16* ws = (_Float16*)d_ws;
  prep_weights<<<144, 512, 0, stream>>>(p, ws);
  GraphTransformer_90237262889124_kernel<<<NSEQ, NTHR, 0, stream>>>(p, ws);
}